// Round 4
// baseline (659.693 us; speedup 1.0000x reference)
//
#include <hip/hip_runtime.h>

// ---------------------------------------------------------------------------
// HedgeHog attention distillation map: pred = (fq.fk^T) rownorm, true = softmax(q0.k0^T/8)
// Output [2,2,16,2048,2048] fp32 = 1.07 GiB -> HBM-write-bound (~170us floor).
//
// v4: the store stream must never drain. k_write has ZERO barriers: each wave
// owns 16 rows + a private LDS transpose buffer; only intra-wave lgkmcnt and
// counted vmcnt waits. 64 rows/block cuts L2 re-reads 4x. Stores are 512B
// contiguous segments (2 rows x 32 lanes x dwordx4).
//  k_proj:    x->q0,k0->fq,fk (bf16, 48MB ws).
//  k_colsum1: fk column-sum partials g_part[bh][8][128] (256 blocks, vec loads).
//  k_write:   per (bh,64 rows): factorized pred sums + register true sums,
//             then stream 128-col chunks barrier-free.
// ---------------------------------------------------------------------------

typedef __attribute__((ext_vector_type(8))) short  bf16x8;
typedef __attribute__((ext_vector_type(4))) float  f32x4;

#define NN 2048
#define NBH 32

__device__ float g_part[NBH * 8 * 128];   // fk colsum partials

__device__ __forceinline__ float bf2f(unsigned short u) {
  union { unsigned int i; float f; } v; v.i = ((unsigned int)u) << 16; return v.f;
}
__device__ __forceinline__ unsigned short f2bf(float f) {
  union { float f; unsigned int i; } v; v.f = f;
  unsigned int x = v.i;
  return (unsigned short)((x + 0x7FFFu + ((x >> 16) & 1u)) >> 16);  // RNE
}
__device__ __forceinline__ bf16x8 cvt8(const float* __restrict__ p) {
  bf16x8 v;
#pragma unroll
  for (int i = 0; i < 8; i++) v[i] = (short)f2bf(p[i]);
  return v;
}
__device__ __forceinline__ f32x4 mfma16(bf16x8 a, bf16x8 b, f32x4 c) {
  return __builtin_amdgcn_mfma_f32_16x16x32_bf16(a, b, c, 0, 0, 0);
}

// ---------------------------------------------------------------------------
// Kernel 1: projections + hedgehog features. One wave owns 16 rows.
// ---------------------------------------------------------------------------
__device__ __forceinline__ void proj_chain(
    const bf16x8 ax[2],
    const float* __restrict__ W1, const float* __restrict__ b1,
    const float* __restrict__ W2, const float* __restrict__ b2,
    unsigned short* __restrict__ o1w, unsigned short* __restrict__ o2w,
    unsigned short (*Tq)[72], unsigned short (*Tf)[136],
    long r0, int l15, int g, int l)
{
#pragma unroll
  for (int nt = 0; nt < 4; nt++) {
    f32x4 acc = {0.f, 0.f, 0.f, 0.f};
    acc = mfma16(ax[0], cvt8(W1 + (nt * 16 + l15) * 64 + g * 8), acc);
    acc = mfma16(ax[1], cvt8(W1 + (nt * 16 + l15) * 64 + 32 + g * 8), acc);
    float bv = b1[nt * 16 + l15];
#pragma unroll
    for (int j = 0; j < 4; j++)
      Tq[g * 4 + j][nt * 16 + l15] = f2bf(acc[j] + bv);   // C layout: row=(l>>4)*4+j, col=l&15
  }
#pragma unroll
  for (int i = 0; i < 2; i++) {
    int c = i * 64 + l;
    int r = c >> 3, cc = c & 7;
    *(bf16x8*)(o1w + (r0 + r) * 64 + cc * 8) = *(const bf16x8*)&Tq[r][cc * 8];
  }
  bf16x8 a1[2];
#pragma unroll
  for (int kk = 0; kk < 2; kk++)
    a1[kk] = *(const bf16x8*)&Tq[l15][kk * 32 + g * 8];
#pragma unroll
  for (int nt = 0; nt < 4; nt++) {
    f32x4 acc = {0.f, 0.f, 0.f, 0.f};
    acc = mfma16(a1[0], cvt8(W2 + (nt * 16 + l15) * 64 + g * 8), acc);
    acc = mfma16(a1[1], cvt8(W2 + (nt * 16 + l15) * 64 + 32 + g * 8), acc);
    float bv = b2[nt * 16 + l15];
#pragma unroll
    for (int j = 0; j < 4; j++) {
      float h = acc[j] + bv;
      Tf[g * 4 + j][nt * 16 + l15]      = f2bf(__expf(h));
      Tf[g * 4 + j][64 + nt * 16 + l15] = f2bf(__expf(-h));
    }
  }
#pragma unroll
  for (int i = 0; i < 4; i++) {
    int c = i * 64 + l;
    int r = c >> 4, cc = c & 15;
    *(bf16x8*)(o2w + (r0 + r) * 128 + cc * 8) = *(const bf16x8*)&Tf[r][cc * 8];
  }
}

__global__ __launch_bounds__(256) void k_proj(
    const float* __restrict__ x,
    const float* __restrict__ Wq,  const float* __restrict__ bq,
    const float* __restrict__ Wk,  const float* __restrict__ bk,
    const float* __restrict__ Wmq, const float* __restrict__ bmq,
    const float* __restrict__ Wmk, const float* __restrict__ bmk,
    unsigned short* __restrict__ q0w, unsigned short* __restrict__ k0w,
    unsigned short* __restrict__ fqw, unsigned short* __restrict__ fkw)
{
  const int tid = threadIdx.x;
  const int w = tid >> 6, l = tid & 63;
  const int l15 = l & 15, g = l >> 4;
  const long r0 = ((long)blockIdx.x * 4 + w) * 16;

  __shared__ unsigned short TqS[4][16][72];
  __shared__ unsigned short TfS[4][16][136];

  bf16x8 ax[2];
#pragma unroll
  for (int kk = 0; kk < 2; kk++)
    ax[kk] = cvt8(x + (r0 + l15) * 64 + kk * 32 + g * 8);

  proj_chain(ax, Wq, bq, Wmq, bmq, q0w, fqw, TqS[w], TfS[w], r0, l15, g, l);
  proj_chain(ax, Wk, bk, Wmk, bmk, k0w, fkw, TqS[w], TfS[w], r0, l15, g, l);
}

// ---------------------------------------------------------------------------
// Kernel 2: fk column-sum partials. Block (bh, part): rows part*256..+255.
// Vectorized: thread (rg=t>>4, cg=t&15) reads bf16x8 of cols cg*8.. over 16 rows.
// ---------------------------------------------------------------------------
__global__ __launch_bounds__(256) void k_colsum1(const unsigned short* __restrict__ fkw)
{
  const int bh = blockIdx.x, part = blockIdx.y;
  const int tid = threadIdx.x;
  const int cg = tid & 15, rg = tid >> 4;
  const unsigned short* fkp = fkw + ((long)bh * NN + part * 256 + rg * 16) * 128 + cg * 8;

  float a8[8] = {0.f, 0.f, 0.f, 0.f, 0.f, 0.f, 0.f, 0.f};
#pragma unroll
  for (int r = 0; r < 16; r++) {
    bf16x8 v = *(const bf16x8*)(fkp + (long)r * 128);
#pragma unroll
    for (int j = 0; j < 8; j++) a8[j] += bf2f((unsigned short)v[j]);
  }
  __shared__ float red[16][132];
#pragma unroll
  for (int j = 0; j < 8; j++) red[rg][cg * 8 + j] = a8[j];
  __syncthreads();
  if (tid < 128) {
    float s = 0.f;
#pragma unroll
    for (int r = 0; r < 16; r++) s += red[r][tid];
    g_part[(bh * 8 + part) * 128 + tid] = s;
  }
}

// ---------------------------------------------------------------------------
// Kernel 3: barrier-free writer. Block = (bh, 64 rows); wave owns 16 rows +
// private LDS buf. Pred sums factorized (g_part), true sums in registers.
// Then 16 chunks x {pred,true}: MFMA -> normalize -> private LDS transpose ->
// 512B-contiguous dwordx4 stores. No __syncthreads anywhere.
// ---------------------------------------------------------------------------
__global__ __launch_bounds__(256, 4) void k_write(
    const unsigned short* __restrict__ q0w, const unsigned short* __restrict__ k0w,
    const unsigned short* __restrict__ fqw, const unsigned short* __restrict__ fkw,
    float* __restrict__ out)
{
  const int bh = blockIdx.x;          // 0..31
  const int rq = blockIdx.y;          // 0..31
  const int tid = threadIdx.x;
  const int w = tid >> 6, l = tid & 63;
  const int l15 = l & 15, g = l >> 4;
  const int qrow0 = rq * 64 + w * 16; // this wave's 16 q-rows

  __shared__ float buf[4][16][132];   // per-wave private transpose buffer

  // ---- A fragments ----
  const unsigned short* fqp = fqw + ((long)bh * NN + qrow0) * 128;
  bf16x8 afq[4];
#pragma unroll
  for (int kk = 0; kk < 4; kk++)
    afq[kk] = *(const bf16x8*)(fqp + l15 * 128 + kk * 32 + g * 8);
  const unsigned short* q0p = q0w + ((long)bh * NN + qrow0) * 64;
  bf16x8 aq0[2];
#pragma unroll
  for (int kk = 0; kk < 2; kk++)
    aq0[kk] = *(const bf16x8*)(q0p + l15 * 64 + kk * 32 + g * 8);

  const unsigned short* fkp = fkw + (long)bh * NN * 128;
  const unsigned short* k0p = k0w + (long)bh * NN * 64;

  // ---- pred reciprocals: ip = 1 / (fq[row] . Sfk), Sfk = sum of partials ----
  float dotv = 0.f;
  {
    const unsigned short* p = fqp + (long)l15 * 128 + g * 32;
    const float* pp = g_part + bh * 1024 + g * 32;
#pragma unroll
    for (int i = 0; i < 32; i += 8) {
      bf16x8 v = *(const bf16x8*)(p + i);
#pragma unroll
      for (int jj = 0; jj < 8; jj++) {
        float s = 0.f;
#pragma unroll
        for (int pt = 0; pt < 8; pt++) s += pp[pt * 128 + i + jj];
        dotv += bf2f((unsigned short)v[jj]) * s;
      }
    }
  }
  dotv += __shfl_xor(dotv, 16, 64);
  dotv += __shfl_xor(dotv, 32, 64);   // every lane: full dot for row (l&15)
  float ip[4];
#pragma unroll
  for (int j = 0; j < 4; j++)
    ip[j] = 1.0f / __shfl(dotv, (g * 4 + j) & 15, 16);

  // ---- true row sums: full k0 scan, register accumulate (per-wave) ----
  float st[4] = {0.f, 0.f, 0.f, 0.f};
  for (int t = 0; t < 128; t++) {
    const unsigned short* bp = k0p + (long)(t * 16 + l15) * 64 + g * 8;
    f32x4 acc = {0.f, 0.f, 0.f, 0.f};
    acc = mfma16(aq0[0], *(const bf16x8*)bp, acc);
    acc = mfma16(aq0[1], *(const bf16x8*)(bp + 32), acc);
#pragma unroll
    for (int j = 0; j < 4; j++) st[j] += __expf(acc[j] * 0.125f);
  }
  float it[4];
#pragma unroll
  for (int j = 0; j < 4; j++) {
    float v = st[j];
    v += __shfl_xor(v, 1, 16);
    v += __shfl_xor(v, 2, 16);
    v += __shfl_xor(v, 4, 16);
    v += __shfl_xor(v, 8, 16);
    it[j] = 1.0f / v;                 // lane's 16-group owns row g*4+j
  }

  // ---- stream 128-col chunks, barrier-free ----
  const long ob_p = (long)bh * NN * NN + (long)qrow0 * NN;
  const long ob_t = ob_p + (long)NBH * NN * NN;
  float (* const mybuf)[132] = buf[w];

  for (int c = 0; c < 16; c++) {
    const int kc = c * 128;
    // ---- pred: 8 tiles -> normalized LDS ----
#pragma unroll
    for (int t = 0; t < 8; t++) {
      const unsigned short* bp = fkp + (long)(kc + t * 16 + l15) * 128 + g * 8;
      f32x4 acc = {0.f, 0.f, 0.f, 0.f};
#pragma unroll
      for (int kk = 0; kk < 4; kk++)
        acc = mfma16(afq[kk], *(const bf16x8*)(bp + kk * 32), acc);
#pragma unroll
      for (int j = 0; j < 4; j++)
        mybuf[g * 4 + j][t * 16 + l15] = acc[j] * ip[j];
    }
    asm volatile("s_waitcnt lgkmcnt(0)" ::: "memory");
#pragma unroll
    for (int i = 0; i < 8; i++) {
      const int r = 2 * i + (l >> 5), cf = (l & 31) * 4;
      f32x4 v = *(const f32x4*)&mybuf[r][cf];
      *(f32x4*)(out + ob_p + (long)r * NN + kc + cf) = v;
    }
    // ---- true: 8 tiles -> normalized LDS ----
#pragma unroll
    for (int t = 0; t < 8; t++) {
      const unsigned short* bp = k0p + (long)(kc + t * 16 + l15) * 64 + g * 8;
      f32x4 acc = {0.f, 0.f, 0.f, 0.f};
      acc = mfma16(aq0[0], *(const bf16x8*)bp, acc);
      acc = mfma16(aq0[1], *(const bf16x8*)(bp + 32), acc);
#pragma unroll
      for (int j = 0; j < 4; j++)
        mybuf[g * 4 + j][t * 16 + l15] = __expf(acc[j] * 0.125f) * it[j];
    }
    asm volatile("s_waitcnt lgkmcnt(0)" ::: "memory");
#pragma unroll
    for (int i = 0; i < 8; i++) {
      const int r = 2 * i + (l >> 5), cf = (l & 31) * 4;
      f32x4 v = *(const f32x4*)&mybuf[r][cf];
      *(f32x4*)(out + ob_t + (long)r * NN + kc + cf) = v;
    }
  }
}

extern "C" void kernel_launch(void* const* d_in, const int* in_sizes, int n_in,
                              void* d_out, int out_size, void* d_ws, size_t ws_size,
                              hipStream_t stream) {
  const float* x   = (const float*)d_in[0];
  const float* Wq  = (const float*)d_in[1];
  const float* bq  = (const float*)d_in[2];
  const float* Wk  = (const float*)d_in[3];
  const float* bk  = (const float*)d_in[4];
  const float* Wmq = (const float*)d_in[5];
  const float* bmq = (const float*)d_in[6];
  const float* Wmk = (const float*)d_in[7];
  const float* bmk = (const float*)d_in[8];
  float* out = (float*)d_out;

  // ws layout (bf16): q0[32][2048][64], k0[...], fq[32][2048][128], fk[...] = 48 MB
  unsigned short* q0w = (unsigned short*)d_ws;
  unsigned short* k0w = q0w + (long)NBH * NN * 64;
  unsigned short* fqw = k0w + (long)NBH * NN * 64;
  unsigned short* fkw = fqw + (long)NBH * NN * 128;

  hipLaunchKernelGGL(k_proj, dim3(1024), dim3(256), 0, stream,
                     x, Wq, bq, Wk, bk, Wmq, bmq, Wmk, bmk, q0w, k0w, fqw, fkw);
  hipLaunchKernelGGL(k_colsum1, dim3(NBH, 8), dim3(256), 0, stream, fkw);
  hipLaunchKernelGGL(k_write, dim3(NBH, 32), dim3(256), 0, stream,
                     q0w, k0w, fqw, fkw, out);
}

// Round 5
// 575.258 us; speedup vs baseline: 1.1468x; 1.1468x over previous
//
#include <hip/hip_runtime.h>

// ---------------------------------------------------------------------------
// HedgeHog attention distillation map: pred = (fq.fk^T) rownorm, true = softmax(q0.k0^T/8)
// Output [2,2,16,2048,2048] fp32 = 1.07 GiB -> HBM-write-bound (~170us floor).
//
// v5: DRAM page locality. v2/v3/v4 all capped at 1.2-1.9 TB/s because the
// chip-wide write stream was 65K interleaved row-streams of 512B-2KB granules
// (every burst on a new DRAM page). fill kernel = few K sequential streams =
// 6.5 TB/s. So: stage HALF a 16-row strip (64KB) in LDS, then store it in pure
// address order (wave w -> rows 4w..4w+3, 4KB sequential per row, 64KB near-
// sequential per block) with nontemporal stores (bypass L2 eviction shuffle).
// 2 blocks/CU overlap compute with stores; plane order staggered per block.
// ---------------------------------------------------------------------------

typedef __attribute__((ext_vector_type(8))) short  bf16x8;
typedef __attribute__((ext_vector_type(4))) float  f32x4;

#define NN 2048
#define NBH 32

__device__ float g_part[NBH * 8 * 128];   // fk colsum partials

__device__ __forceinline__ float bf2f(unsigned short u) {
  union { unsigned int i; float f; } v; v.i = ((unsigned int)u) << 16; return v.f;
}
__device__ __forceinline__ unsigned short f2bf(float f) {
  union { float f; unsigned int i; } v; v.f = f;
  unsigned int x = v.i;
  return (unsigned short)((x + 0x7FFFu + ((x >> 16) & 1u)) >> 16);  // RNE
}
__device__ __forceinline__ bf16x8 cvt8(const float* __restrict__ p) {
  bf16x8 v;
#pragma unroll
  for (int i = 0; i < 8; i++) v[i] = (short)f2bf(p[i]);
  return v;
}
__device__ __forceinline__ f32x4 mfma16(bf16x8 a, bf16x8 b, f32x4 c) {
  return __builtin_amdgcn_mfma_f32_16x16x32_bf16(a, b, c, 0, 0, 0);
}

// ---------------------------------------------------------------------------
// Kernel 1: projections + hedgehog features. One wave owns 16 rows.
// ---------------------------------------------------------------------------
__device__ __forceinline__ void proj_chain(
    const bf16x8 ax[2],
    const float* __restrict__ W1, const float* __restrict__ b1,
    const float* __restrict__ W2, const float* __restrict__ b2,
    unsigned short* __restrict__ o1w, unsigned short* __restrict__ o2w,
    unsigned short (*Tq)[72], unsigned short (*Tf)[136],
    long r0, int l15, int g, int l)
{
#pragma unroll
  for (int nt = 0; nt < 4; nt++) {
    f32x4 acc = {0.f, 0.f, 0.f, 0.f};
    acc = mfma16(ax[0], cvt8(W1 + (nt * 16 + l15) * 64 + g * 8), acc);
    acc = mfma16(ax[1], cvt8(W1 + (nt * 16 + l15) * 64 + 32 + g * 8), acc);
    float bv = b1[nt * 16 + l15];
#pragma unroll
    for (int j = 0; j < 4; j++)
      Tq[g * 4 + j][nt * 16 + l15] = f2bf(acc[j] + bv);   // C layout: row=(l>>4)*4+j, col=l&15
  }
#pragma unroll
  for (int i = 0; i < 2; i++) {
    int c = i * 64 + l;
    int r = c >> 3, cc = c & 7;
    *(bf16x8*)(o1w + (r0 + r) * 64 + cc * 8) = *(const bf16x8*)&Tq[r][cc * 8];
  }
  bf16x8 a1[2];
#pragma unroll
  for (int kk = 0; kk < 2; kk++)
    a1[kk] = *(const bf16x8*)&Tq[l15][kk * 32 + g * 8];
#pragma unroll
  for (int nt = 0; nt < 4; nt++) {
    f32x4 acc = {0.f, 0.f, 0.f, 0.f};
    acc = mfma16(a1[0], cvt8(W2 + (nt * 16 + l15) * 64 + g * 8), acc);
    acc = mfma16(a1[1], cvt8(W2 + (nt * 16 + l15) * 64 + 32 + g * 8), acc);
    float bv = b2[nt * 16 + l15];
#pragma unroll
    for (int j = 0; j < 4; j++) {
      float h = acc[j] + bv;
      Tf[g * 4 + j][nt * 16 + l15]      = f2bf(__expf(h));
      Tf[g * 4 + j][64 + nt * 16 + l15] = f2bf(__expf(-h));
    }
  }
#pragma unroll
  for (int i = 0; i < 4; i++) {
    int c = i * 64 + l;
    int r = c >> 4, cc = c & 15;
    *(bf16x8*)(o2w + (r0 + r) * 128 + cc * 8) = *(const bf16x8*)&Tf[r][cc * 8];
  }
}

__global__ __launch_bounds__(256) void k_proj(
    const float* __restrict__ x,
    const float* __restrict__ Wq,  const float* __restrict__ bq,
    const float* __restrict__ Wk,  const float* __restrict__ bk,
    const float* __restrict__ Wmq, const float* __restrict__ bmq,
    const float* __restrict__ Wmk, const float* __restrict__ bmk,
    unsigned short* __restrict__ q0w, unsigned short* __restrict__ k0w,
    unsigned short* __restrict__ fqw, unsigned short* __restrict__ fkw)
{
  const int tid = threadIdx.x;
  const int w = tid >> 6, l = tid & 63;
  const int l15 = l & 15, g = l >> 4;
  const long r0 = ((long)blockIdx.x * 4 + w) * 16;

  __shared__ unsigned short TqS[4][16][72];
  __shared__ unsigned short TfS[4][16][136];

  bf16x8 ax[2];
#pragma unroll
  for (int kk = 0; kk < 2; kk++)
    ax[kk] = cvt8(x + (r0 + l15) * 64 + kk * 32 + g * 8);

  proj_chain(ax, Wq, bq, Wmq, bmq, q0w, fqw, TqS[w], TfS[w], r0, l15, g, l);
  proj_chain(ax, Wk, bk, Wmk, bmk, k0w, fkw, TqS[w], TfS[w], r0, l15, g, l);
}

// ---------------------------------------------------------------------------
// Kernel 2: fk column-sum partials (bh, part): rows part*256..+255.
// ---------------------------------------------------------------------------
__global__ __launch_bounds__(256) void k_colsum1(const unsigned short* __restrict__ fkw)
{
  const int bh = blockIdx.x, part = blockIdx.y;
  const int tid = threadIdx.x;
  const int cg = tid & 15, rg = tid >> 4;
  const unsigned short* fkp = fkw + ((long)bh * NN + part * 256 + rg * 16) * 128 + cg * 8;

  float a8[8] = {0.f, 0.f, 0.f, 0.f, 0.f, 0.f, 0.f, 0.f};
#pragma unroll
  for (int r = 0; r < 16; r++) {
    bf16x8 v = *(const bf16x8*)(fkp + (long)r * 128);
#pragma unroll
    for (int j = 0; j < 8; j++) a8[j] += bf2f((unsigned short)v[j]);
  }
  __shared__ float red[16][132];
#pragma unroll
  for (int j = 0; j < 8; j++) red[rg][cg * 8 + j] = a8[j];
  __syncthreads();
  if (tid < 128) {
    float s = 0.f;
#pragma unroll
    for (int r = 0; r < 16; r++) s += red[r][tid];
    g_part[(bh * 8 + part) * 128 + tid] = s;
  }
}

// ---------------------------------------------------------------------------
// Kernel 3: strip writer. Block = (bh, 16 q-rows). 4 phases: {pred,true} x
// {half0,half1}. Compute 16x1024 normalized fp32 into LDS, barrier, store in
// address order (wave w -> rows 4w..4w+3, 4KB runs, nontemporal), barrier.
// ---------------------------------------------------------------------------
__global__ __launch_bounds__(256, 2) void k_write(
    const unsigned short* __restrict__ q0w, const unsigned short* __restrict__ k0w,
    const unsigned short* __restrict__ fqw, const unsigned short* __restrict__ fkw,
    float* __restrict__ out)
{
  const int bh = blockIdx.x;          // 0..31
  const int rq = blockIdx.y;          // 0..127
  const int tid = threadIdx.x;
  const int w = tid >> 6, l = tid & 63;
  const int l15 = l & 15, g = l >> 4;
  const int qrow0 = rq * 16;

  __shared__ float buf[16][1032];     // 64KB half-strip (stride pad: 1032)
  __shared__ float sred[4][16];

  // ---- A fragments ----
  const unsigned short* fqp = fqw + ((long)bh * NN + qrow0) * 128;
  bf16x8 afq[4];
#pragma unroll
  for (int kk = 0; kk < 4; kk++)
    afq[kk] = *(const bf16x8*)(fqp + l15 * 128 + kk * 32 + g * 8);
  const unsigned short* q0p = q0w + ((long)bh * NN + qrow0) * 64;
  bf16x8 aq0[2];
#pragma unroll
  for (int kk = 0; kk < 2; kk++)
    aq0[kk] = *(const bf16x8*)(q0p + l15 * 64 + kk * 32 + g * 8);

  const unsigned short* fkp = fkw + (long)bh * NN * 128;
  const unsigned short* k0p = k0w + (long)bh * NN * 64;

  // ---- pred reciprocals: ip = 1 / (fq[row] . Sfk) ----
  float dotv = 0.f;
  {
    const unsigned short* p = fqp + (long)l15 * 128 + g * 32;
    const float* pp = g_part + bh * 1024 + g * 32;
#pragma unroll
    for (int i = 0; i < 32; i += 8) {
      bf16x8 v = *(const bf16x8*)(p + i);
#pragma unroll
      for (int jj = 0; jj < 8; jj++) {
        float s = 0.f;
#pragma unroll
        for (int pt = 0; pt < 8; pt++) s += pp[pt * 128 + i + jj];
        dotv += bf2f((unsigned short)v[jj]) * s;
      }
    }
  }
  dotv += __shfl_xor(dotv, 16, 64);
  dotv += __shfl_xor(dotv, 32, 64);
  float ip[4];
#pragma unroll
  for (int j = 0; j < 4; j++)
    ip[j] = 1.0f / __shfl(dotv, (g * 4 + j) & 15, 16);

  // ---- true row sums (keys split across waves, LDS combine) ----
  float st[4] = {0.f, 0.f, 0.f, 0.f};
  for (int t = w; t < 128; t += 4) {
    const unsigned short* bp = k0p + (long)(t * 16 + l15) * 64 + g * 8;
    f32x4 acc = {0.f, 0.f, 0.f, 0.f};
    acc = mfma16(aq0[0], *(const bf16x8*)bp, acc);
    acc = mfma16(aq0[1], *(const bf16x8*)(bp + 32), acc);
#pragma unroll
    for (int j = 0; j < 4; j++) st[j] += __expf(acc[j] * 0.125f);
  }
#pragma unroll
  for (int j = 0; j < 4; j++) {
    float v = st[j];
    v += __shfl_xor(v, 1, 16);
    v += __shfl_xor(v, 2, 16);
    v += __shfl_xor(v, 4, 16);
    v += __shfl_xor(v, 8, 16);
    if (l15 == 0) sred[w][g * 4 + j] = v;
  }
  __syncthreads();
  float it[4];
#pragma unroll
  for (int j = 0; j < 4; j++)
    it[j] = 1.0f / (sred[0][g * 4 + j] + sred[1][g * 4 + j] +
                    sred[2][g * 4 + j] + sred[3][g * 4 + j]);
  __syncthreads();

  // ---- 4 phases: plane x half, plane order staggered per block ----
  const long ob_p = (long)bh * NN * NN + (long)qrow0 * NN;
  const long ob_t = ob_p + (long)NBH * NN * NN;
  const int sw = (bh ^ rq) & 1;

  for (int ph = 0; ph < 4; ph++) {
    const int plane = (ph >> 1) ^ sw;   // 0=pred, 1=true
    const int h = ph & 1;               // column half
    if (plane == 0) {
      // pred: 16 tiles per wave (cols w*256 + tt*16 within half)
#pragma unroll
      for (int tt = 0; tt < 16; tt++) {
        const int colh = w * 256 + tt * 16;
        const unsigned short* bp = fkp + (long)(h * 1024 + colh + l15) * 128 + g * 8;
        f32x4 acc = {0.f, 0.f, 0.f, 0.f};
#pragma unroll
        for (int kk = 0; kk < 4; kk++)
          acc = mfma16(afq[kk], *(const bf16x8*)(bp + kk * 32), acc);
#pragma unroll
        for (int j = 0; j < 4; j++)
          buf[g * 4 + j][colh + l15] = acc[j] * ip[j];
      }
    } else {
#pragma unroll
      for (int tt = 0; tt < 16; tt++) {
        const int colh = w * 256 + tt * 16;
        const unsigned short* bp = k0p + (long)(h * 1024 + colh + l15) * 64 + g * 8;
        f32x4 acc = {0.f, 0.f, 0.f, 0.f};
        acc = mfma16(aq0[0], *(const bf16x8*)bp, acc);
        acc = mfma16(aq0[1], *(const bf16x8*)(bp + 32), acc);
#pragma unroll
        for (int j = 0; j < 4; j++)
          buf[g * 4 + j][colh + l15] = __expf(acc[j] * 0.125f) * it[j];
      }
    }
    __syncthreads();
    // store: wave w -> rows 4w..4w+3, each row 4KB sequential, nontemporal
    {
      const long ob = (plane == 0 ? ob_p : ob_t) + h * 1024;
#pragma unroll
      for (int r = 0; r < 4; r++) {
        const int row = w * 4 + r;
        float* orow = out + ob + (long)row * NN;
#pragma unroll
        for (int i = 0; i < 4; i++) {
          f32x4 v = *(const f32x4*)&buf[row][i * 256 + l * 4];
          __builtin_nontemporal_store(v, (f32x4*)(orow + i * 256 + l * 4));
        }
      }
    }
    __syncthreads();
  }
}

extern "C" void kernel_launch(void* const* d_in, const int* in_sizes, int n_in,
                              void* d_out, int out_size, void* d_ws, size_t ws_size,
                              hipStream_t stream) {
  const float* x   = (const float*)d_in[0];
  const float* Wq  = (const float*)d_in[1];
  const float* bq  = (const float*)d_in[2];
  const float* Wk  = (const float*)d_in[3];
  const float* bk  = (const float*)d_in[4];
  const float* Wmq = (const float*)d_in[5];
  const float* bmq = (const float*)d_in[6];
  const float* Wmk = (const float*)d_in[7];
  const float* bmk = (const float*)d_in[8];
  float* out = (float*)d_out;

  // ws layout (bf16): q0[32][2048][64], k0[...], fq[32][2048][128], fk[...] = 48 MB
  unsigned short* q0w = (unsigned short*)d_ws;
  unsigned short* k0w = q0w + (long)NBH * NN * 64;
  unsigned short* fqw = k0w + (long)NBH * NN * 64;
  unsigned short* fkw = fqw + (long)NBH * NN * 128;

  hipLaunchKernelGGL(k_proj, dim3(1024), dim3(256), 0, stream,
                     x, Wq, bq, Wk, bk, Wmq, bmq, Wmk, bmk, q0w, k0w, fqw, fkw);
  hipLaunchKernelGGL(k_colsum1, dim3(NBH, 8), dim3(256), 0, stream, fkw);
  hipLaunchKernelGGL(k_write, dim3(NBH, 128), dim3(256), 0, stream,
                     q0w, k0w, fqw, fkw, out);
}